// Round 3
// baseline (1324.128 us; speedup 1.0000x reference)
//
#include <hip/hip_runtime.h>
#include <cstddef>

#define NH 32
#define TSEQ 2048

typedef short bf16x8_t __attribute__((ext_vector_type(8)));
typedef float f32x4_t  __attribute__((ext_vector_type(4)));

__device__ __forceinline__ float b2f(short u) {
  unsigned v = ((unsigned)(unsigned short)u) << 16;
  return __builtin_bit_cast(float, v);
}
__device__ __forceinline__ short f2b(float f) {
  unsigned u = __builtin_bit_cast(unsigned, f);
  u = u + 0x7fffu + ((u >> 16) & 1u);   // RNE; inputs never NaN/Inf here
  return (short)(u >> 16);
}

// ------------- fp32 -> bf16 conversion, column slice [col0, col0+w8*8) -----------------
__global__ __launch_bounds__(256) void conv_cols(
    const float* __restrict__ in, short* __restrict__ out,
    int rows, int ncols, int col0, int w8) {
  int g = blockIdx.x * 256 + threadIdx.x;
  if (g >= rows * w8) return;
  int r = g / w8, c8 = g - r * w8;
  const float* p = in + (size_t)r * ncols + col0 + c8 * 8;
  float4 a = *reinterpret_cast<const float4*>(p);
  float4 b = *reinterpret_cast<const float4*>(p + 4);
  bf16x8_t v;
  v[0] = f2b(a.x); v[1] = f2b(a.y); v[2] = f2b(a.z); v[3] = f2b(a.w);
  v[4] = f2b(b.x); v[5] = f2b(b.y); v[6] = f2b(b.z); v[7] = f2b(b.w);
  *reinterpret_cast<bf16x8_t*>(out + (size_t)g * 8) = v;
}

// ---------------- GEMM: C[M][ldc] = A[M][K] * B[K][N] (+bias), bf16 in, bf16/f32 out ---
// B compact [K][N]; transposed into LDS with k-rotation swizzle (rot = 8*((n>>3)&7)).
// 128x128 tile, BK=64, 256 threads (4 waves), each wave 64x64 via 4x4 16x16x32 MFMA.
template <bool NGUARD, bool BIAS, bool F32OUT>
__global__ __launch_bounds__(256) void gemm_nn(
    const short* __restrict__ A, const short* __restrict__ B,
    const float* __restrict__ bias, void* __restrict__ Cv,
    int M, int N, int K, int ldc) {
  __shared__ bf16x8_t Alds[128][9];
  __shared__ __align__(16) short Blds[128][72];   // [n][rotated k]
  const int tid = threadIdx.x;
  const int wave = tid >> 6, lane = tid & 63, quad = lane >> 4, l16 = lane & 15;
  const int m0 = blockIdx.y * 128, n0 = blockIdx.x * 128;
  const int wm = (wave >> 1) * 64, wn = (wave & 1) * 64;
  const int srow = tid >> 3, sk = tid & 7;        // A staging
  const int bk = tid >> 4, bn0 = (tid & 15) * 8;  // B staging
  const int brot = (tid & 7) * 8;                 // = 8*((bn0>>3)&7)

  f32x4_t acc[4][4];
#pragma unroll
  for (int i = 0; i < 4; ++i)
#pragma unroll
    for (int j = 0; j < 4; ++j) {
      acc[i][j][0] = 0.f; acc[i][j][1] = 0.f; acc[i][j][2] = 0.f; acc[i][j][3] = 0.f;
    }

  for (int k0 = 0; k0 < K; k0 += 64) {
    __syncthreads();
#pragma unroll
    for (int cc = 0; cc < 4; ++cc) {
      int row = srow + cc * 32;
      Alds[row][sk] = *reinterpret_cast<const bf16x8_t*>(A + (size_t)(m0 + row) * K + k0 + sk * 8);
    }
#pragma unroll
    for (int cc = 0; cc < 4; ++cc) {
      int krow = bk + cc * 16;
      bf16x8_t v;
      if (!NGUARD || (n0 + bn0) < N) {
        v = *reinterpret_cast<const bf16x8_t*>(B + (size_t)(k0 + krow) * N + n0 + bn0);
      } else {
#pragma unroll
        for (int z = 0; z < 8; ++z) v[z] = 0;
      }
      int slot = (krow + brot) & 63;
#pragma unroll
      for (int j = 0; j < 8; ++j) Blds[bn0 + j][slot] = v[j];
    }
    __syncthreads();
#pragma unroll
    for (int s = 0; s < 2; ++s) {
      bf16x8_t af[4], bfr[4];
#pragma unroll
      for (int i = 0; i < 4; ++i) af[i] = Alds[wm + i * 16 + l16][s * 4 + quad];
#pragma unroll
      for (int j = 0; j < 4; ++j) {
        int n = wn + j * 16 + l16;
        int rot = ((n >> 3) & 7) * 8;
        int start = (s * 32 + quad * 8 + rot) & 63;
        bfr[j] = *reinterpret_cast<const bf16x8_t*>(&Blds[n][start]);
      }
#pragma unroll
      for (int i = 0; i < 4; ++i)
#pragma unroll
        for (int j = 0; j < 4; ++j)
          acc[i][j] = __builtin_amdgcn_mfma_f32_16x16x32_bf16(af[i], bfr[j], acc[i][j], 0, 0, 0);
    }
  }
  // epilogue: C/D layout: row = quad*4 + r, col = l16
#pragma unroll
  for (int j = 0; j < 4; ++j) {
    int col = n0 + wn + j * 16 + l16;
    if (NGUARD && col >= N) continue;
    float bv = BIAS ? bias[col] : 0.0f;
#pragma unroll
    for (int i = 0; i < 4; ++i) {
      int rowb = m0 + wm + i * 16 + quad * 4;
#pragma unroll
      for (int r = 0; r < 4; ++r) {
        if constexpr (F32OUT) {
          ((float*)Cv)[(size_t)(rowb + r) * ldc + col] = acc[i][j][r] + bv;
        } else {
          ((short*)Cv)[(size_t)(rowb + r) * ldc + col] = f2b(acc[i][j][r] + bv);
        }
      }
    }
  }
}

// ---------------- RMSNorm over 1536 cols (bf16 x, fp32 g), one block per row -----------
__global__ __launch_bounds__(256) void rmsnorm1536(
    const short* __restrict__ x, const float* __restrict__ g, short* __restrict__ y) {
  const int t = blockIdx.x, tid = threadIdx.x;
  const short* row = x + (size_t)t * 1536;
  float v[6], ss = 0.f;
#pragma unroll
  for (int i = 0; i < 6; ++i) { v[i] = b2f(row[tid + i * 256]); ss += v[i] * v[i]; }
#pragma unroll
  for (int off = 1; off < 64; off <<= 1) ss += __shfl_xor(ss, off, 64);
  __shared__ float red[4];
  if ((tid & 63) == 0) red[tid >> 6] = ss;
  __syncthreads();
  float tot = red[0] + red[1] + red[2] + red[3];
  float sc = rsqrtf(tot * (1.0f / 1536.0f) + 1e-6f);
#pragma unroll
  for (int i = 0; i < 6; ++i)
    y[(size_t)t * 1536 + tid + i * 256] = f2b(v[i] * sc * g[tid + i * 256]);
}

// ---------------- kv_a RMSNorm (512, fp32 g) + k_pe RoPE (64), one block per row -------
__global__ __launch_bounds__(256) void kvnormrope(
    const short* __restrict__ latent, const float* __restrict__ gkv,
    const int* __restrict__ pos, short* __restrict__ kvn, short* __restrict__ kpe) {
  const int t = blockIdx.x, tid = threadIdx.x;
  const short* row = latent + (size_t)t * 576;
  float v0 = b2f(row[tid]), v1 = b2f(row[tid + 256]);
  float ss = v0 * v0 + v1 * v1;
#pragma unroll
  for (int off = 1; off < 64; off <<= 1) ss += __shfl_xor(ss, off, 64);
  __shared__ float red[4];
  if ((tid & 63) == 0) red[tid >> 6] = ss;
  __syncthreads();
  float tot = red[0] + red[1] + red[2] + red[3];
  float sc = rsqrtf(tot * (1.0f / 512.0f) + 1e-6f);
  kvn[(size_t)t * 512 + tid]       = f2b(v0 * sc * gkv[tid]);
  kvn[(size_t)t * 512 + tid + 256] = f2b(v1 * sc * gkv[tid + 256]);
  if (tid < 32) {
    float x1 = b2f(row[512 + 2 * tid]), x2 = b2f(row[512 + 2 * tid + 1]);
    float p = (float)pos[t];
    float inv = powf(10000.0f, -(float)tid / 32.0f);
    float f = p * inv;
    float sn = sinf(f), cs = cosf(f);
    kpe[(size_t)t * 64 + 2 * tid]     = f2b(x1 * cs - x2 * sn);
    kpe[(size_t)t * 64 + 2 * tid + 1] = f2b(x1 * sn + x2 * cs);
  }
}

// ---------------- in-place RoPE on q_pe slice of q [T][H*192] -------------------------
__global__ __launch_bounds__(256) void ropeq(short* __restrict__ q, const int* __restrict__ pos) {
  int idx = blockIdx.x * 256 + threadIdx.x;  // T*H*32 pairs
  int i = idx & 31, h = (idx >> 5) & 31, t = idx >> 10;
  size_t base = (size_t)t * 6144 + h * 192 + 128 + 2 * i;
  float x1 = b2f(q[base]), x2 = b2f(q[base + 1]);
  float p = (float)pos[t];
  float inv = powf(10000.0f, -(float)i / 32.0f);
  float f = p * inv;
  float sn = sinf(f), cs = cosf(f);
  q[base]     = f2b(x1 * cs - x2 * sn);
  q[base + 1] = f2b(x1 * sn + x2 * cs);
}

// ---------------- flash attention: BQ=BK=64, one block per (q-tile, head) -------------
// q: [T][H*192] (nope|roped pe), kv: [T][H*256] (k_nope|v), kpe: [T][64], obuf: [T][H*128]
__global__ __launch_bounds__(256) void attn_k(
    const short* __restrict__ q, const short* __restrict__ kv,
    const short* __restrict__ kpe, short* __restrict__ obuf) {
  const int qt = blockIdx.x, h = blockIdx.y;
  const int q0 = qt * 64;
  const int tid = threadIdx.x, wave = tid >> 6, lane = tid & 63, quad = lane >> 4, l16 = lane & 15;
  const float scale = 0.072168784f;  // 1/sqrt(192)
  const float NEG = -1e30f;

  __shared__ __align__(16) short Vlds[128][72];       // [vd][krow], krow rotated by vd>>3
  __shared__ __align__(16) short Plds[4][16][72];     // per-wave P strip [qrow16][krow64]

  bf16x8_t aq[6];
  {
    const size_t qr = (size_t)(q0 + wave * 16 + l16) * (NH * 192) + (size_t)h * 192;
#pragma unroll
    for (int s = 0; s < 6; ++s)
      aq[s] = *reinterpret_cast<const bf16x8_t*>(q + qr + s * 32 + quad * 8);
  }

  f32x4_t oacc[8];
#pragma unroll
  for (int j = 0; j < 8; ++j) { oacc[j][0] = 0.f; oacc[j][1] = 0.f; oacc[j][2] = 0.f; oacc[j][3] = 0.f; }
  float m_run[4], l_run[4];
#pragma unroll
  for (int r = 0; r < 4; ++r) { m_run[r] = NEG; l_run[r] = 0.f; }

  for (int kt = 0; kt <= qt; ++kt) {
    const int k0 = kt * 64;
    __syncthreads();
#pragma unroll
    for (int cc = 0; cc < 4; ++cc) {
      int c = tid + cc * 256;
      int krow = c >> 4, vd0 = (c & 15) * 8;
      bf16x8_t v = *reinterpret_cast<const bf16x8_t*>(
          kv + (size_t)(k0 + krow) * (NH * 256) + (size_t)h * 256 + 128 + vd0);
      int rot = ((c & 7)) * 8;   // 8*((vd0>>3)&7)
#pragma unroll
      for (int j = 0; j < 8; ++j) Vlds[vd0 + j][(krow + rot) & 63] = v[j];
    }
    f32x4_t sacc[4];
#pragma unroll
    for (int nt = 0; nt < 4; ++nt) { sacc[nt][0] = 0.f; sacc[nt][1] = 0.f; sacc[nt][2] = 0.f; sacc[nt][3] = 0.f; }
#pragma unroll
    for (int nt = 0; nt < 4; ++nt) {
      const int trow = k0 + nt * 16 + l16;
      const short* kvrow = kv + (size_t)trow * (NH * 256) + (size_t)h * 256;
      const short* kperow = kpe + (size_t)trow * 64;
#pragma unroll
      for (int s = 0; s < 6; ++s) {
        bf16x8_t bk;
        if (s < 4) bk = *reinterpret_cast<const bf16x8_t*>(kvrow + s * 32 + quad * 8);
        else       bk = *reinterpret_cast<const bf16x8_t*>(kperow + (s - 4) * 32 + quad * 8);
        sacc[nt] = __builtin_amdgcn_mfma_f32_16x16x32_bf16(aq[s], bk, sacc[nt], 0, 0, 0);
      }
    }
    const bool diag = (kt == qt);
    float p[4][4], mt[4];
#pragma unroll
    for (int r = 0; r < 4; ++r) mt[r] = NEG;
#pragma unroll
    for (int nt = 0; nt < 4; ++nt) {
      int kabs = k0 + nt * 16 + l16;
#pragma unroll
      for (int r = 0; r < 4; ++r) {
        float v = sacc[nt][r] * scale;
        if (diag) {
          int qabs = q0 + wave * 16 + quad * 4 + r;
          if (kabs > qabs) v = NEG;
        }
        p[nt][r] = v;
        mt[r] = fmaxf(mt[r], v);
      }
    }
#pragma unroll
    for (int off = 1; off < 16; off <<= 1)
#pragma unroll
      for (int r = 0; r < 4; ++r) mt[r] = fmaxf(mt[r], __shfl_xor(mt[r], off, 64));
    float alpha[4], sums[4];
#pragma unroll
    for (int r = 0; r < 4; ++r) {
      float mnew = fmaxf(m_run[r], mt[r]);
      alpha[r] = __expf(m_run[r] - mnew);
      m_run[r] = mnew;
      float s = 0.f;
#pragma unroll
      for (int nt = 0; nt < 4; ++nt) { float e = __expf(p[nt][r] - mnew); p[nt][r] = e; s += e; }
      sums[r] = s;
    }
#pragma unroll
    for (int off = 1; off < 16; off <<= 1)
#pragma unroll
      for (int r = 0; r < 4; ++r) sums[r] += __shfl_xor(sums[r], off, 64);
#pragma unroll
    for (int r = 0; r < 4; ++r) l_run[r] = l_run[r] * alpha[r] + sums[r];
#pragma unroll
    for (int j = 0; j < 8; ++j)
#pragma unroll
      for (int r = 0; r < 4; ++r) oacc[j][r] *= alpha[r];
#pragma unroll
    for (int nt = 0; nt < 4; ++nt)
#pragma unroll
      for (int r = 0; r < 4; ++r)
        Plds[wave][quad * 4 + r][nt * 16 + l16] = f2b(p[nt][r]);
    __syncthreads();
#pragma unroll
    for (int s2 = 0; s2 < 2; ++s2) {
      bf16x8_t ap = *reinterpret_cast<const bf16x8_t*>(&Plds[wave][l16][s2 * 32 + quad * 8]);
#pragma unroll
      for (int j = 0; j < 8; ++j) {
        int vd = j * 16 + l16;
        int rot = ((vd >> 3) & 7) * 8;
        int start = (s2 * 32 + quad * 8 + rot) & 63;
        bf16x8_t bv = *reinterpret_cast<const bf16x8_t*>(&Vlds[vd][start]);
        oacc[j] = __builtin_amdgcn_mfma_f32_16x16x32_bf16(ap, bv, oacc[j], 0, 0, 0);
      }
    }
  }
#pragma unroll
  for (int r = 0; r < 4; ++r) {
    int t = q0 + wave * 16 + quad * 4 + r;
    float inv = 1.0f / l_run[r];
#pragma unroll
    for (int j = 0; j < 8; ++j)
      obuf[(size_t)t * (NH * 128) + (size_t)h * 128 + j * 16 + l16] = f2b(oacc[j][r] * inv);
  }
}

extern "C" void kernel_launch(void* const* d_in, const int* in_sizes, int n_in,
                              void* d_out, int out_size, void* d_ws, size_t ws_size,
                              hipStream_t stream) {
  const float* h     = (const float*)d_in[0];
  const int*   pos   = (const int*)d_in[1];
  const float* Wq_a  = (const float*)d_in[2];
  const float* gq    = (const float*)d_in[3];
  const float* Wq_b  = (const float*)d_in[4];
  const float* Wkv_a = (const float*)d_in[5];
  const float* bkva  = (const float*)d_in[6];
  const float* gkv   = (const float*)d_in[7];
  const float* Wkv_b = (const float*)d_in[8];
  const float* Wo    = (const float*)d_in[9];
  float* out = (float*)d_out;

  // Workspace overlays (peak 75,759,616 B ≈ 72.3 MB):
  //  [0, 33.55M)        kvbuf [2048][8192]      (written by gemm4, read by attn)
  //    h_bf overlay     [0, 20.97M)             (conv -> gemm1a/b, gemm3; dead before gemm4)
  //    Wbuf overlay     [20.97M, 33.55M)        (q-path weight slices + Wkv_a; dead before gemm4)
  //  [33.55M, 58.72M)   qbuf [2048][6144]       (gemm2 -> attn)
  //  [58.72M, 75.50M)   obuf [2048][4096]       (attn -> gemm5)
  //    ql     overlay   [58.72M, 65.01M)
  //    qn     overlay   [65.01M, 71.30M)
  //    latent overlay   [58.72M, 61.08M)
  //    kvn    overlay   [61.08M, 63.18M)
  //    Wkv_b  overlay   [63.18M, 71.57M)
  //  [75.50M, 75.76M)   kpe [2048][64]          (kvnormrope -> attn)
  //  gemm5 time: Wo_bf at [0, 41.94M) over dead kvbuf+qbuf-head
  char* ws = (char*)d_ws;
  short* kvbuf  = (short*)(ws);
  short* h_bf   = (short*)(ws);
  short* Wbuf   = (short*)(ws + 20971520);
  short* qbuf   = (short*)(ws + 33554432);
  short* obuf   = (short*)(ws + 58720256);
  short* ql     = (short*)(ws + 58720256);
  short* qn     = (short*)(ws + 65011712);
  short* latent = (short*)(ws + 58720256);
  short* kvn    = (short*)(ws + 61079552);
  short* Wkvb_b = (short*)(ws + 63176704);
  short* kpe    = (short*)(ws + 75497472);
  short* Wo_bf  = (short*)(ws);

  dim3 blk(256);
  auto cgrid = [](long long n8) { return dim3((unsigned)((n8 + 255) / 256)); };

  // h -> bf16
  conv_cols<<<cgrid(2048LL * 640), blk, 0, stream>>>(h, h_bf, 2048, 5120, 0, 640);

  // q path: ql = h @ Wq_a (N split 2x768); qn = rmsnorm(ql); qbuf = qn @ Wq_b (2x3072); rope
  conv_cols<<<cgrid(5120LL * 96), blk, 0, stream>>>(Wq_a, Wbuf, 5120, 1536, 0, 96);
  gemm_nn<false, false, false><<<dim3(6, 16), blk, 0, stream>>>(h_bf, Wbuf, nullptr, ql, 2048, 768, 5120, 1536);
  conv_cols<<<cgrid(5120LL * 96), blk, 0, stream>>>(Wq_a, Wbuf, 5120, 1536, 768, 96);
  gemm_nn<false, false, false><<<dim3(6, 16), blk, 0, stream>>>(h_bf, Wbuf, nullptr, ql + 768, 2048, 768, 5120, 1536);
  rmsnorm1536<<<2048, blk, 0, stream>>>(ql, gq, qn);
  conv_cols<<<cgrid(1536LL * 384), blk, 0, stream>>>(Wq_b, Wbuf, 1536, 6144, 0, 384);
  gemm_nn<false, false, false><<<dim3(24, 16), blk, 0, stream>>>(qn, Wbuf, nullptr, qbuf, 2048, 3072, 1536, 6144);
  conv_cols<<<cgrid(1536LL * 384), blk, 0, stream>>>(Wq_b, Wbuf, 1536, 6144, 3072, 384);
  gemm_nn<false, false, false><<<dim3(24, 16), blk, 0, stream>>>(qn, Wbuf, nullptr, qbuf + 3072, 2048, 3072, 1536, 6144);
  ropeq<<<8192, blk, 0, stream>>>(qbuf, pos);

  // kv path: latent = h @ Wkv_a + b; kvn,kpe; kvbuf = kvn @ Wkv_b
  conv_cols<<<cgrid(5120LL * 72), blk, 0, stream>>>(Wkv_a, Wbuf, 5120, 576, 0, 72);
  gemm_nn<true, true, false><<<dim3(5, 16), blk, 0, stream>>>(h_bf, Wbuf, bkva, latent, 2048, 576, 5120, 576);
  kvnormrope<<<2048, blk, 0, stream>>>(latent, gkv, pos, kvn, kpe);
  conv_cols<<<cgrid(512LL * 1024), blk, 0, stream>>>(Wkv_b, Wkvb_b, 512, 8192, 0, 1024);
  gemm_nn<false, false, false><<<dim3(64, 16), blk, 0, stream>>>(kvn, Wkvb_b, nullptr, kvbuf, 2048, 8192, 512, 8192);

  // attention + output projection (fp32 out)
  attn_k<<<dim3(32, 32), blk, 0, stream>>>(qbuf, kvbuf, kpe, obuf);
  conv_cols<<<cgrid(4096LL * 640), blk, 0, stream>>>(Wo, Wo_bf, 4096, 5120, 0, 640);
  gemm_nn<false, false, true><<<dim3(40, 16), blk, 0, stream>>>(obuf, Wo_bf, nullptr, out, 2048, 5120, 4096, 5120);
}

// Round 4
// 972.134 us; speedup vs baseline: 1.3621x; 1.3621x over previous
//
#include <hip/hip_runtime.h>
#include <cstddef>

#define NH 32
#define TSEQ 2048

typedef short bf16x8_t __attribute__((ext_vector_type(8)));
typedef float f32x4_t  __attribute__((ext_vector_type(4)));

__device__ __forceinline__ float b2f(short u) {
  unsigned v = ((unsigned)(unsigned short)u) << 16;
  return __builtin_bit_cast(float, v);
}
__device__ __forceinline__ short f2b(float f) {
  unsigned u = __builtin_bit_cast(unsigned, f);
  u = u + 0x7fffu + ((u >> 16) & 1u);   // RNE; inputs never NaN/Inf here
  return (short)(u >> 16);
}

// ------------- fp32 -> bf16 row-major convert (for h) ---------------------------------
__global__ __launch_bounds__(256) void conv_full(
    const float* __restrict__ in, short* __restrict__ out, long long n8) {
  long long g = (long long)blockIdx.x * 256 + threadIdx.x;
  if (g >= n8) return;
  const float* p = in + g * 8;
  float4 a = *reinterpret_cast<const float4*>(p);
  float4 b = *reinterpret_cast<const float4*>(p + 4);
  bf16x8_t v;
  v[0] = f2b(a.x); v[1] = f2b(a.y); v[2] = f2b(a.z); v[3] = f2b(a.w);
  v[4] = f2b(b.x); v[5] = f2b(b.y); v[6] = f2b(b.z); v[7] = f2b(b.w);
  *reinterpret_cast<bf16x8_t*>(out + g * 8) = v;
}

// ------------- fused transpose + fp32->bf16: in[R][ldin] (submatrix R x C) -> out[C][R]
// grid (C/64, R/64). Coalesced fp32 reads, coalesced bf16 writes.
__global__ __launch_bounds__(256) void tconv(
    const float* __restrict__ in, short* __restrict__ out, int R, int ldin) {
  __shared__ short tile[64][72];
  const int tid = threadIdx.x;
  const int c0 = blockIdx.x * 64, r0 = blockIdx.y * 64;
#pragma unroll
  for (int cc = 0; cc < 2; ++cc) {
    int idx = tid + cc * 256;
    int row = idx >> 3, col = (idx & 7) * 8;
    const float* p = in + (size_t)(r0 + row) * ldin + c0 + col;
    float4 a = *reinterpret_cast<const float4*>(p);
    float4 b = *reinterpret_cast<const float4*>(p + 4);
    short* t = &tile[row][col];
    t[0] = f2b(a.x); t[1] = f2b(a.y); t[2] = f2b(a.z); t[3] = f2b(a.w);
    t[4] = f2b(b.x); t[5] = f2b(b.y); t[6] = f2b(b.z); t[7] = f2b(b.w);
  }
  __syncthreads();
#pragma unroll
  for (int cc = 0; cc < 2; ++cc) {
    int idx = tid + cc * 256;
    int orow = idx >> 3, ocol = (idx & 7) * 8;   // orow = input col, ocol = input row base
    bf16x8_t v;
#pragma unroll
    for (int j = 0; j < 8; ++j) v[j] = tile[ocol + j][orow];
    *reinterpret_cast<bf16x8_t*>(out + (size_t)(c0 + orow) * R + r0 + ocol) = v;
  }
}

// ---------------- GEMM: C[M][ldc] = A[M][K] * Bt[N][K]^T (+bias), bf16 in, bf16/f32 out
// Both operands k-contiguous; both staged with vector b128 writes into +16B-padded LDS.
// 128x128 tile, BK=64, 256 threads (4 waves), each wave 64x64 via 4x4 16x16x32 MFMA.
template <bool NGUARD, bool BIAS, bool F32OUT>
__global__ __launch_bounds__(256) void gemm_btt(
    const short* __restrict__ A, const short* __restrict__ Bt,
    const float* __restrict__ bias, void* __restrict__ Cv,
    int M, int N, int K, int ldc) {
  __shared__ bf16x8_t Alds[128][9];
  __shared__ bf16x8_t Blds[128][9];
  const int tid = threadIdx.x;
  const int wave = tid >> 6, lane = tid & 63, quad = lane >> 4, l16 = lane & 15;
  const int m0 = blockIdx.y * 128, n0 = blockIdx.x * 128;
  const int wm = (wave >> 1) * 64, wn = (wave & 1) * 64;
  const int srow = tid >> 3, sk = tid & 7;

  f32x4_t acc[4][4];
#pragma unroll
  for (int i = 0; i < 4; ++i)
#pragma unroll
    for (int j = 0; j < 4; ++j) {
      acc[i][j][0] = 0.f; acc[i][j][1] = 0.f; acc[i][j][2] = 0.f; acc[i][j][3] = 0.f;
    }

  for (int k0 = 0; k0 < K; k0 += 64) {
    __syncthreads();
#pragma unroll
    for (int cc = 0; cc < 4; ++cc) {
      int row = srow + cc * 32;
      Alds[row][sk] = *reinterpret_cast<const bf16x8_t*>(A + (size_t)(m0 + row) * K + k0 + sk * 8);
      bf16x8_t bv;
      if (!NGUARD || (n0 + row) < N) {
        bv = *reinterpret_cast<const bf16x8_t*>(Bt + (size_t)(n0 + row) * K + k0 + sk * 8);
      } else {
#pragma unroll
        for (int z = 0; z < 8; ++z) bv[z] = 0;
      }
      Blds[row][sk] = bv;
    }
    __syncthreads();
#pragma unroll
    for (int s = 0; s < 2; ++s) {
      bf16x8_t af[4], bfr[4];
#pragma unroll
      for (int i = 0; i < 4; ++i) af[i] = Alds[wm + i * 16 + l16][s * 4 + quad];
#pragma unroll
      for (int j = 0; j < 4; ++j) bfr[j] = Blds[wn + j * 16 + l16][s * 4 + quad];
#pragma unroll
      for (int i = 0; i < 4; ++i)
#pragma unroll
        for (int j = 0; j < 4; ++j)
          acc[i][j] = __builtin_amdgcn_mfma_f32_16x16x32_bf16(af[i], bfr[j], acc[i][j], 0, 0, 0);
    }
  }
  // epilogue: C/D layout: row = quad*4 + r, col = l16
#pragma unroll
  for (int j = 0; j < 4; ++j) {
    int col = n0 + wn + j * 16 + l16;
    if (NGUARD && col >= N) continue;
    float bv = BIAS ? bias[col] : 0.0f;
#pragma unroll
    for (int i = 0; i < 4; ++i) {
      int rowb = m0 + wm + i * 16 + quad * 4;
#pragma unroll
      for (int r = 0; r < 4; ++r) {
        if constexpr (F32OUT) {
          ((float*)Cv)[(size_t)(rowb + r) * ldc + col] = acc[i][j][r] + bv;
        } else {
          ((short*)Cv)[(size_t)(rowb + r) * ldc + col] = f2b(acc[i][j][r] + bv);
        }
      }
    }
  }
}

// ---------------- RMSNorm over 1536 cols (bf16 x, fp32 g), one block per row -----------
__global__ __launch_bounds__(256) void rmsnorm1536(
    const short* __restrict__ x, const float* __restrict__ g, short* __restrict__ y) {
  const int t = blockIdx.x, tid = threadIdx.x;
  const short* row = x + (size_t)t * 1536;
  float v[6], ss = 0.f;
#pragma unroll
  for (int i = 0; i < 6; ++i) { v[i] = b2f(row[tid + i * 256]); ss += v[i] * v[i]; }
#pragma unroll
  for (int off = 1; off < 64; off <<= 1) ss += __shfl_xor(ss, off, 64);
  __shared__ float red[4];
  if ((tid & 63) == 0) red[tid >> 6] = ss;
  __syncthreads();
  float tot = red[0] + red[1] + red[2] + red[3];
  float sc = rsqrtf(tot * (1.0f / 1536.0f) + 1e-6f);
#pragma unroll
  for (int i = 0; i < 6; ++i)
    y[(size_t)t * 1536 + tid + i * 256] = f2b(v[i] * sc * g[tid + i * 256]);
}

// ---------------- kv_a RMSNorm (512, fp32 g) + k_pe RoPE (64), one block per row -------
__global__ __launch_bounds__(256) void kvnormrope(
    const short* __restrict__ latent, const float* __restrict__ gkv,
    const int* __restrict__ pos, short* __restrict__ kvn, short* __restrict__ kpe) {
  const int t = blockIdx.x, tid = threadIdx.x;
  const short* row = latent + (size_t)t * 576;
  float v0 = b2f(row[tid]), v1 = b2f(row[tid + 256]);
  float ss = v0 * v0 + v1 * v1;
#pragma unroll
  for (int off = 1; off < 64; off <<= 1) ss += __shfl_xor(ss, off, 64);
  __shared__ float red[4];
  if ((tid & 63) == 0) red[tid >> 6] = ss;
  __syncthreads();
  float tot = red[0] + red[1] + red[2] + red[3];
  float sc = rsqrtf(tot * (1.0f / 512.0f) + 1e-6f);
  kvn[(size_t)t * 512 + tid]       = f2b(v0 * sc * gkv[tid]);
  kvn[(size_t)t * 512 + tid + 256] = f2b(v1 * sc * gkv[tid + 256]);
  if (tid < 32) {
    float x1 = b2f(row[512 + 2 * tid]), x2 = b2f(row[512 + 2 * tid + 1]);
    float p = (float)pos[t];
    float inv = powf(10000.0f, -(float)tid / 32.0f);
    float f = p * inv;
    float sn = sinf(f), cs = cosf(f);
    kpe[(size_t)t * 64 + 2 * tid]     = f2b(x1 * cs - x2 * sn);
    kpe[(size_t)t * 64 + 2 * tid + 1] = f2b(x1 * sn + x2 * cs);
  }
}

// ---------------- in-place RoPE on q_pe slice of q [T][H*192] -------------------------
__global__ __launch_bounds__(256) void ropeq(short* __restrict__ q, const int* __restrict__ pos) {
  int idx = blockIdx.x * 256 + threadIdx.x;  // T*H*32 pairs
  int i = idx & 31, h = (idx >> 5) & 31, t = idx >> 10;
  size_t base = (size_t)t * 6144 + h * 192 + 128 + 2 * i;
  float x1 = b2f(q[base]), x2 = b2f(q[base + 1]);
  float p = (float)pos[t];
  float inv = powf(10000.0f, -(float)i / 32.0f);
  float f = p * inv;
  float sn = sinf(f), cs = cosf(f);
  q[base]     = f2b(x1 * cs - x2 * sn);
  q[base + 1] = f2b(x1 * sn + x2 * cs);
}

// ---------------- flash attention: BQ=BK=64, one block per (q-tile, head) -------------
// q: [T][H*192] (nope|roped pe), kv: [T][H*256] (k_nope|v), kpe: [T][64], obuf: [T][H*128]
// K tile staged into padded LDS with coalesced loads (was: per-wave global gathers).
__global__ __launch_bounds__(256) void attn_k(
    const short* __restrict__ q, const short* __restrict__ kv,
    const short* __restrict__ kpe, short* __restrict__ obuf) {
  const int qt = 31 - blockIdx.x;   // longest blocks first
  const int h = blockIdx.y;
  const int q0 = qt * 64;
  const int tid = threadIdx.x, wave = tid >> 6, lane = tid & 63, quad = lane >> 4, l16 = lane & 15;
  const float scale = 0.072168784f;  // 1/sqrt(192)
  const float NEG = -1e30f;

  __shared__ __align__(16) short Klds[64][200];   // [krow][d 0..191 + 8 pad]; stride 400B
  __shared__ __align__(16) short Vlds[128][72];   // [vd][krow], krow rotated by vd>>3
  __shared__ __align__(16) short Plds[4][16][72]; // per-wave P strip [qrow16][krow64]

  bf16x8_t aq[6];
  {
    const size_t qr = (size_t)(q0 + wave * 16 + l16) * (NH * 192) + (size_t)h * 192;
#pragma unroll
    for (int s = 0; s < 6; ++s)
      aq[s] = *reinterpret_cast<const bf16x8_t*>(q + qr + s * 32 + quad * 8);
  }

  f32x4_t oacc[8];
#pragma unroll
  for (int j = 0; j < 8; ++j) { oacc[j][0] = 0.f; oacc[j][1] = 0.f; oacc[j][2] = 0.f; oacc[j][3] = 0.f; }
  float m_run[4], l_run[4];
#pragma unroll
  for (int r = 0; r < 4; ++r) { m_run[r] = NEG; l_run[r] = 0.f; }

  for (int kt = 0; kt <= qt; ++kt) {
    const int k0 = kt * 64;
    __syncthreads();   // prior iteration's LDS reads complete
    // stage K tile: 64 rows x 24 chunks (16 k_nope from kv + 8 from kpe), coalesced b128
#pragma unroll
    for (int i = 0; i < 6; ++i) {
      int c = tid + i * 256;              // 0..1535
      int krow = c / 24, sub = c - krow * 24;
      const short* src = (sub < 16)
          ? kv + (size_t)(k0 + krow) * (NH * 256) + (size_t)h * 256 + sub * 8
          : kpe + (size_t)(k0 + krow) * 64 + (sub - 16) * 8;
      *reinterpret_cast<bf16x8_t*>(&Klds[krow][sub * 8]) =
          *reinterpret_cast<const bf16x8_t*>(src);
    }
    // stage V transposed: Vlds[vd][rot(krow)] = kv[k0+krow][h*256+128+vd]
#pragma unroll
    for (int cc = 0; cc < 4; ++cc) {
      int c = tid + cc * 256;
      int krow = c >> 4, vd0 = (c & 15) * 8;
      bf16x8_t v = *reinterpret_cast<const bf16x8_t*>(
          kv + (size_t)(k0 + krow) * (NH * 256) + (size_t)h * 256 + 128 + vd0);
      int rot = (c & 7) * 8;   // 8*((vd0>>3)&7)
#pragma unroll
      for (int j = 0; j < 8; ++j) Vlds[vd0 + j][(krow + rot) & 63] = v[j];
    }
    __syncthreads();
    // S = Q K^T, K fragments from LDS (2-way conflict max: row stride 100 words)
    f32x4_t sacc[4];
#pragma unroll
    for (int nt = 0; nt < 4; ++nt) { sacc[nt][0] = 0.f; sacc[nt][1] = 0.f; sacc[nt][2] = 0.f; sacc[nt][3] = 0.f; }
#pragma unroll
    for (int nt = 0; nt < 4; ++nt) {
#pragma unroll
      for (int s = 0; s < 6; ++s) {
        bf16x8_t bk = *reinterpret_cast<const bf16x8_t*>(&Klds[nt * 16 + l16][s * 32 + quad * 8]);
        sacc[nt] = __builtin_amdgcn_mfma_f32_16x16x32_bf16(aq[s], bk, sacc[nt], 0, 0, 0);
      }
    }
    const bool diag = (kt == qt);
    float p[4][4], mt[4];
#pragma unroll
    for (int r = 0; r < 4; ++r) mt[r] = NEG;
#pragma unroll
    for (int nt = 0; nt < 4; ++nt) {
      int kabs = k0 + nt * 16 + l16;
#pragma unroll
      for (int r = 0; r < 4; ++r) {
        float v = sacc[nt][r] * scale;
        if (diag) {
          int qabs = q0 + wave * 16 + quad * 4 + r;
          if (kabs > qabs) v = NEG;
        }
        p[nt][r] = v;
        mt[r] = fmaxf(mt[r], v);
      }
    }
#pragma unroll
    for (int off = 1; off < 16; off <<= 1)
#pragma unroll
      for (int r = 0; r < 4; ++r) mt[r] = fmaxf(mt[r], __shfl_xor(mt[r], off, 64));
    float alpha[4], sums[4];
#pragma unroll
    for (int r = 0; r < 4; ++r) {
      float mnew = fmaxf(m_run[r], mt[r]);
      alpha[r] = __expf(m_run[r] - mnew);
      m_run[r] = mnew;
      float s = 0.f;
#pragma unroll
      for (int nt = 0; nt < 4; ++nt) { float e = __expf(p[nt][r] - mnew); p[nt][r] = e; s += e; }
      sums[r] = s;
    }
#pragma unroll
    for (int off = 1; off < 16; off <<= 1)
#pragma unroll
      for (int r = 0; r < 4; ++r) sums[r] += __shfl_xor(sums[r], off, 64);
#pragma unroll
    for (int r = 0; r < 4; ++r) l_run[r] = l_run[r] * alpha[r] + sums[r];
#pragma unroll
    for (int j = 0; j < 8; ++j)
#pragma unroll
      for (int r = 0; r < 4; ++r) oacc[j][r] *= alpha[r];
    // write P to own wave's strip (C layout -> [qrow][krow]); same-wave read below,
    // lgkmcnt ordering suffices (no barrier needed between write & read)
#pragma unroll
    for (int nt = 0; nt < 4; ++nt)
#pragma unroll
      for (int r = 0; r < 4; ++r)
        Plds[wave][quad * 4 + r][nt * 16 + l16] = f2b(p[nt][r]);
    // O += P V
#pragma unroll
    for (int s2 = 0; s2 < 2; ++s2) {
      bf16x8_t ap = *reinterpret_cast<const bf16x8_t*>(&Plds[wave][l16][s2 * 32 + quad * 8]);
#pragma unroll
      for (int j = 0; j < 8; ++j) {
        int vd = j * 16 + l16;
        int rot = ((vd >> 3) & 7) * 8;
        int start = (s2 * 32 + quad * 8 + rot) & 63;
        bf16x8_t bv = *reinterpret_cast<const bf16x8_t*>(&Vlds[vd][start]);
        oacc[j] = __builtin_amdgcn_mfma_f32_16x16x32_bf16(ap, bv, oacc[j], 0, 0, 0);
      }
    }
  }
#pragma unroll
  for (int r = 0; r < 4; ++r) {
    int t = q0 + wave * 16 + quad * 4 + r;
    float inv = 1.0f / l_run[r];
#pragma unroll
    for (int j = 0; j < 8; ++j)
      obuf[(size_t)t * (NH * 128) + (size_t)h * 128 + j * 16 + l16] = f2b(oacc[j][r] * inv);
  }
}

extern "C" void kernel_launch(void* const* d_in, const int* in_sizes, int n_in,
                              void* d_out, int out_size, void* d_ws, size_t ws_size,
                              hipStream_t stream) {
  const float* h     = (const float*)d_in[0];
  const int*   pos   = (const int*)d_in[1];
  const float* Wq_a  = (const float*)d_in[2];
  const float* gq    = (const float*)d_in[3];
  const float* Wq_b  = (const float*)d_in[4];
  const float* Wkv_a = (const float*)d_in[5];
  const float* bkva  = (const float*)d_in[6];
  const float* gkv   = (const float*)d_in[7];
  const float* Wkv_b = (const float*)d_in[8];
  const float* Wo    = (const float*)d_in[9];
  float* out = (float*)d_out;

  // Workspace overlays (peak 75,759,616 B — proven budget):
  //  [0, 33.55M)        kvbuf [2048][8192]
  //    h_bf   overlay   [0, 20.97M)        (steps 1-5; dead before kvbuf write)
  //    WqaT   overlay   [20.97M, 36.70M)   (step 2 only; tail crosses into dead qbuf space)
  //    WkvaT  overlay   [20.97M, 26.87M)   (step 5)
  //    WqbT_h overlay   [20.97M, 30.41M)   (step 4, two 3072x1536 halves)
  //    WoT    overlay   [0, 41.94M)        (step 9; kvbuf+qbuf dead)
  //  [33.55M, 58.72M)   qbuf [2048][6144]  (written step 4)
  //  [58.72M, 75.50M)   obuf [2048][4096]  (written step 8)
  //    ql     overlay   [58.72M, 65.01M)
  //    qn     overlay   [65.01M, 71.30M)
  //    latent overlay   [58.72M, 61.08M)
  //    kvn    overlay   [61.08M, 63.18M)
  //    WkvbT  overlay   [63.18M, 71.57M)
  //  [75.50M, 75.76M)   kpe [2048][64]
  char* ws = (char*)d_ws;
  short* kvbuf  = (short*)(ws);
  short* h_bf   = (short*)(ws);
  short* Wslot  = (short*)(ws + 20971520);   // WqaT / WkvaT / WqbT halves
  short* qbuf   = (short*)(ws + 33554432);
  short* obuf   = (short*)(ws + 58720256);
  short* ql     = (short*)(ws + 58720256);
  short* qn     = (short*)(ws + 65011712);
  short* latent = (short*)(ws + 58720256);
  short* kvn    = (short*)(ws + 61079552);
  short* WkvbT  = (short*)(ws + 63176704);
  short* kpe    = (short*)(ws + 75497472);
  short* WoT    = (short*)(ws);

  dim3 blk(256);

  // h -> bf16
  conv_full<<<dim3((unsigned)((2048LL * 640 + 255) / 256)), blk, 0, stream>>>(h, h_bf, 2048LL * 640);

  // q path: ql = h @ Wq_a ; qn = rmsnorm ; qbuf = qn @ Wq_b (2 N-halves) ; rope
  tconv<<<dim3(24, 80), blk, 0, stream>>>(Wq_a, Wslot, 5120, 1536);
  gemm_btt<false, false, false><<<dim3(12, 16), blk, 0, stream>>>(h_bf, Wslot, nullptr, ql, 2048, 1536, 5120, 1536);
  rmsnorm1536<<<2048, blk, 0, stream>>>(ql, gq, qn);
  tconv<<<dim3(48, 24), blk, 0, stream>>>(Wq_b, Wslot, 1536, 6144);
  gemm_btt<false, false, false><<<dim3(24, 16), blk, 0, stream>>>(qn, Wslot, nullptr, qbuf, 2048, 3072, 1536, 6144);
  tconv<<<dim3(48, 24), blk, 0, stream>>>(Wq_b + 3072, Wslot, 1536, 6144);
  gemm_btt<false, false, false><<<dim3(24, 16), blk, 0, stream>>>(qn, Wslot, nullptr, qbuf + 3072, 2048, 3072, 1536, 6144);
  ropeq<<<8192, blk, 0, stream>>>(qbuf, pos);

  // kv path: latent = h @ Wkv_a + b ; kvn,kpe ; kvbuf = kvn @ Wkv_b
  tconv<<<dim3(9, 80), blk, 0, stream>>>(Wkv_a, Wslot, 5120, 576);
  gemm_btt<true, true, false><<<dim3(5, 16), blk, 0, stream>>>(h_bf, Wslot, bkva, latent, 2048, 576, 5120, 576);
  kvnormrope<<<2048, blk, 0, stream>>>(latent, gkv, pos, kvn, kpe);
  tconv<<<dim3(128, 8), blk, 0, stream>>>(Wkv_b, WkvbT, 512, 8192);
  gemm_btt<false, false, false><<<dim3(64, 16), blk, 0, stream>>>(kvn, WkvbT, nullptr, kvbuf, 2048, 8192, 512, 8192);

  // attention + output projection (fp32 out)
  attn_k<<<dim3(32, 32), blk, 0, stream>>>(qbuf, kvbuf, kpe, obuf);
  tconv<<<dim3(80, 64), blk, 0, stream>>>(Wo, WoT, 4096, 5120);
  gemm_btt<false, false, true><<<dim3(40, 16), blk, 0, stream>>>(obuf, WoT, nullptr, out, 2048, 5120, 4096, 5120);
}